// Round 5
// baseline (1239.696 us; speedup 1.0000x reference)
//
#include <hip/hip_runtime.h>
#include <math.h>

#define DD 128
#define EDD 64

typedef __attribute__((ext_vector_type(8))) short bf16x8;
typedef __attribute__((ext_vector_type(4))) float f32x4;

__device__ inline unsigned short f2bf(float f) {
    unsigned int u = __float_as_uint(f);
    u += 0x7FFFu + ((u >> 16) & 1u);
    return (unsigned short)(u >> 16);
}
__device__ inline unsigned int pack2bf16(float lo, float hi) {
    return (unsigned int)f2bf(lo) | ((unsigned int)f2bf(hi) << 16);
}

// ---------------- fused q/k/v/skip linears: 4 rows per 128-thread block ----------------
__global__ __launch_bounds__(128) void lin4_kernel(
    const float* __restrict__ x,
    const float* __restrict__ Wq, const float* __restrict__ bq,
    const float* __restrict__ Wk, const float* __restrict__ bk,
    const float* __restrict__ Wv, const float* __restrict__ bv,
    const float* __restrict__ Ws, const float* __restrict__ bs,
    float* __restrict__ q, float* __restrict__ k, float* __restrict__ v,
    float* __restrict__ pre, int N)
{
    __shared__ float xs[4][DD];
    int tid = threadIdx.x;
    int r0 = blockIdx.x * 4;
    for (int r = 0; r < 4; r++) {
        int row = r0 + r;
        xs[r][tid] = (row < N) ? x[(size_t)row * DD + tid] : 0.f;
    }
    __syncthreads();
    float aq[4], ak[4], av[4], as_[4];
    float bqv = bq[tid], bkv = bk[tid], bvv = bv[tid], bsv = bs[tid];
    #pragma unroll
    for (int r = 0; r < 4; r++) { aq[r] = bqv; ak[r] = bkv; av[r] = bvv; as_[r] = bsv; }
    for (int kk = 0; kk < DD; kk++) {
        float wq = Wq[kk * DD + tid], wk = Wk[kk * DD + tid];
        float wv = Wv[kk * DD + tid], ws = Ws[kk * DD + tid];
        #pragma unroll
        for (int r = 0; r < 4; r++) {
            float xv = xs[r][kk];
            aq[r] += xv * wq; ak[r] += xv * wk; av[r] += xv * wv; as_[r] += xv * ws;
        }
    }
    for (int r = 0; r < 4; r++) {
        int row = r0 + r;
        if (row >= N) break;
        size_t o = (size_t)row * DD + tid;
        q[o] = aq[r]; k[o] = ak[r]; v[o] = av[r];
        pre[o] = xs[r][tid] + as_[r];   // x + (x@Ws + bs)
    }
}

// ---------------- histogram ----------------
__global__ void count_kernel(const int* __restrict__ idx, int n, int* __restrict__ cnt)
{
    int i = blockIdx.x * blockDim.x + threadIdx.x;
    int stride = gridDim.x * blockDim.x;
    for (; i < n; i += stride) atomicAdd(&cnt[idx[i]], 1);
}

// ---------------- single-block exclusive scan ----------------
__global__ __launch_bounds__(1024) void scan_kernel(const int* __restrict__ deg, int N,
                                                    int* __restrict__ indptr, int* __restrict__ fill)
{
    __shared__ int s[1024];
    int tid = threadIdx.x;
    int running = 0;
    for (int base = 0; base < N; base += 1024) {
        int i = base + tid;
        int val = (i < N) ? deg[i] : 0;
        s[tid] = val; __syncthreads();
        for (int off = 1; off < 1024; off <<= 1) {
            int t = (tid >= off) ? s[tid - off] : 0;
            __syncthreads();
            s[tid] += t;
            __syncthreads();
        }
        int excl = s[tid] - val;
        if (i < N) { indptr[i] = running + excl; fill[i] = running + excl; }
        int tot = s[1023];
        __syncthreads();
        running += tot;
    }
    if (tid == 0) indptr[N] = running;
}

// ---------------- scatter edge ids into dst-CSR ----------------
__global__ void escatter_kernel(const int* __restrict__ srcA, const int* __restrict__ dstA, int E,
                                int* __restrict__ fill, int* __restrict__ ssrc, int* __restrict__ seid)
{
    int i = blockIdx.x * blockDim.x + threadIdx.x;
    int stride = gridDim.x * blockDim.x;
    for (; i < E; i += stride) {
        int d = dstA[i];
        int pos = atomicAdd(&fill[d], 1);
        ssrc[pos] = srcA[i];
        seid[pos] = i;
    }
}

// ---------------- scatter subgraph rows into segment-sorted order ----------------
__global__ void sscatter_kernel(const int* __restrict__ sub_nodes, const int* __restrict__ sub_ind,
                                int M, int* __restrict__ sfill,
                                int* __restrict__ snode, int* __restrict__ sseg)
{
    int i = blockIdx.x * blockDim.x + threadIdx.x;
    int stride = gridDim.x * blockDim.x;
    for (; i < M; i += stride) {
        int seg = sub_ind[i];
        int pos = atomicAdd(&sfill[seg], 1);
        snode[pos] = sub_nodes[i];
        sseg[pos] = seg;
    }
}

// ---------------- attention v4: no-rescale exact softmax (alpha is O(1)-bounded), prefetch ----------------
__global__ __launch_bounds__(512, 6) void attn_kernel(
    const float* __restrict__ q, const float* __restrict__ k, const float* __restrict__ v,
    const float* __restrict__ edge_attr, const float* __restrict__ We, const float* __restrict__ be,
    const int* __restrict__ indptr, const int* __restrict__ ssrc, const int* __restrict__ seid,
    float* __restrict__ pre, int N)
{
    __shared__ float WeT[DD * 65];   // WeT[c*65 + j] = We[j*128 + c]
    int tid = threadIdx.x;
    for (int idx = tid; idx < EDD * DD; idx += 512) {
        int j = idx >> 7, c = idx & 127;
        WeT[c * 65 + j] = We[idx];
    }
    __syncthreads();

    int wave = tid >> 6, lane = tid & 63;
    int n = blockIdx.x * 8 + wave;
    if (n >= N) return;

    int jj = lane & 7;
    int gbase = lane & 56;
    int c0 = lane * 2;

    float2 qv  = *(const float2*)&q[(size_t)n * DD + c0];
    float2 bev = *(const float2*)&be[c0];

    // qbe4 = (q . be) / 4, uniform per head group
    float t = qv.x * bev.x + qv.y * bev.y;
    t += __shfl_xor(t, 1); t += __shfl_xor(t, 2); t += __shfl_xor(t, 4);
    float qbe4 = t * 0.25f;

    // qWe[r] = sum_c q[n,16g+c] * We[jj+8r][16g+c]
    float qWe[8];
    #pragma unroll
    for (int r = 0; r < 8; r++) qWe[r] = 0.f;
    #pragma unroll
    for (int cc = 0; cc < 8; cc++) {
        float q0 = __shfl(qv.x, gbase + cc);
        float q1 = __shfl(qv.y, gbase + cc);
        const float* w0 = &WeT[((gbase << 1) + 2 * cc) * 65 + jj];
        const float* w1 = w0 + 65;
        #pragma unroll
        for (int r = 0; r < 8; r++)
            qWe[r] += q0 * w0[8 * r] + q1 * w1[8 * r];
    }

    int start = indptr[n], end = indptr[n + 1];
    float s = 0.f, av0 = 0.f, av1 = 0.f;
    float aea[8];
    #pragma unroll
    for (int r = 0; r < 8; r++) aea[r] = 0.f;

    // 1-deep prefetch
    float ea_p = 0.f; float2 kv_p = {0.f, 0.f}, vv_p = {0.f, 0.f};
    if (start < end) {
        int src = ssrc[start], eid = seid[start];
        ea_p = edge_attr[(size_t)eid * EDD + lane];
        kv_p = *(const float2*)&k[(size_t)src * DD + c0];
        vv_p = *(const float2*)&v[(size_t)src * DD + c0];
    }

    for (int ii = start; ii < end; ii++) {
        float  ea_c = ea_p;
        float2 kv_c = kv_p, vv_c = vv_p;
        if (ii + 1 < end) {
            int src = ssrc[ii + 1], eid = seid[ii + 1];
            ea_p = edge_attr[(size_t)eid * EDD + lane];
            kv_p = *(const float2*)&k[(size_t)src * DD + c0];
            vv_p = *(const float2*)&v[(size_t)src * DD + c0];
        }
        float ear[8];
        #pragma unroll
        for (int r = 0; r < 8; r++) ear[r] = __shfl(ea_c, jj + 8 * r);
        float part = qv.x * kv_c.x + qv.y * kv_c.y;
        #pragma unroll
        for (int r = 0; r < 8; r++) part += ear[r] * qWe[r];
        part += __shfl_xor(part, 1);
        part += __shfl_xor(part, 2);
        part += __shfl_xor(part, 4);
        float p = __expf(part * 0.25f + qbe4);   // exact softmax numerator (no max shift; alpha O(1))
        s += p;
        av0 += p * vv_c.x;
        av1 += p * vv_c.y;
        #pragma unroll
        for (int r = 0; r < 8; r++) aea[r] += p * ear[r];
    }

    if (end > start) {
        float inv = 1.f / s;
        // oe[c0] = sum_j aea[g][j] * We[j][c0], read from WeT (bank-friendly: 2L+j -> 2-way max)
        float oe0 = 0.f, oe1 = 0.f;
        const float* wr0 = &WeT[c0 * 65];
        const float* wr1 = &WeT[(c0 + 1) * 65];
        #pragma unroll
        for (int j = 0; j < 64; j += 2) {
            float a0 = __shfl(aea[j >> 3], gbase + (j & 7));
            float a1 = __shfl(aea[(j + 1) >> 3], gbase + ((j + 1) & 7));
            float2 w0 = *(const float2*)&wr0[j];
            float2 w1 = *(const float2*)&wr1[j];
            oe0 += a0 * w0.x + a1 * w0.y;
            oe1 += a0 * w1.x + a1 * w1.y;
        }
        size_t o = (size_t)n * DD + c0;
        pre[o]     += (av0 + oe0) * inv + bev.x;
        pre[o + 1] += (av1 + oe1) * inv + bev.y;
    }
}

// ---------------- pack a [128][128] fp32 weight into bf16 MFMA B-fragment order ----------------
__global__ __launch_bounds__(256) void packw_kernel(const float* __restrict__ w,
                                                    unsigned short* __restrict__ packed)
{
    int idx = blockIdx.x * 256 + threadIdx.x;
    if (idx >= DD * DD) return;
    int j    = idx & 7;
    int lane = (idx >> 3) & 63;
    int kt   = (idx >> 9) & 3;
    int ncf  = idx >> 11;
    int kk  = kt * 32 + (lane >> 4) * 8 + j;
    int col = ncf * 16 + (lane & 15);
    packed[idx] = f2bf(w[kk * DD + col]);
}

// ---------------- subgraph branch: segment-sorted, in-place LDS, run-length reduced atomics ----------------
__global__ __launch_bounds__(256, 8) void submlp_mfma_kernel(
    const float* __restrict__ x, const int* __restrict__ snode, const int* __restrict__ sseg,
    const float* __restrict__ sn_g, const float* __restrict__ sn_b,
    const unsigned short* __restrict__ packB1, const float* __restrict__ p1b,
    const unsigned short* __restrict__ packB2, const float* __restrict__ p2b,
    float* __restrict__ accum, int M)
{
    __shared__ unsigned short sxs[64 * DD];   // 16 KB; reused in-place for hs, then fp32 out half-tile
    __shared__ int segS[64];
    float* outS = (float*)sxs;

    int tid = threadIdx.x;
    int lane = tid & 63, wid = tid >> 6;
    size_t m0 = (size_t)blockIdx.x * 64;

    if (tid < 64) {
        size_t row = m0 + tid;
        segS[tid] = (row < (size_t)M) ? sseg[row] : -1;
    }

    {
        int nid = 0;
        {
            size_t row = m0 + wid * 16 + (lane & 15);
            if (lane < 16 && row < (size_t)M) nid = snode[row];
        }
        float g0 = sn_g[2 * lane], g1 = sn_g[2 * lane + 1];
        float b0 = sn_b[2 * lane], b1 = sn_b[2 * lane + 1];
        #pragma unroll
        for (int r = 0; r < 16; r++) {
            int tr = wid * 16 + r;
            size_t row = m0 + tr;
            int node = __shfl(nid, r);
            float v0 = 0.f, v1 = 0.f;
            if (row < (size_t)M) {
                float2 xv = *(const float2*)&x[(size_t)node * DD + 2 * lane];
                v0 = xv.x; v1 = xv.y;
            }
            float s1 = v0 + v1, s2 = v0 * v0 + v1 * v1;
            #pragma unroll
            for (int o = 32; o >= 1; o >>= 1) { s1 += __shfl_xor(s1, o); s2 += __shfl_xor(s2, o); }
            float mean = s1 * (1.f / DD);
            float var  = s2 * (1.f / DD) - mean * mean;
            float rs = rsqrtf(var + 1e-5f);
            float n0 = (v0 - mean) * rs * g0 + b0;
            float n1 = (v1 - mean) * rs * g1 + b1;
            unsigned int uidx = ((unsigned)(tr * 64 + lane)) ^ (((unsigned)tr & 7u) << 2);
            ((unsigned int*)sxs)[uidx] = pack2bf16(n0, n1);
        }
    }
    __syncthreads();

    int wr = wid >> 1, wc = wid & 1;
    int rA = wr * 32 + (lane & 15);
    int kb = (lane >> 4) * 8;

    f32x4 acc[2][4];
    #pragma unroll
    for (int i = 0; i < 2; i++)
        #pragma unroll
        for (int j = 0; j < 4; j++) acc[i][j] = (f32x4){0.f, 0.f, 0.f, 0.f};

    #pragma unroll
    for (int kt = 0; kt < 4; kt++) {
        int k0 = kt * 32 + kb;
        bf16x8 a0 = *(const bf16x8*)&sxs[((rA)      * DD + k0) ^ ((rA & 7) << 3)];
        int rA1 = rA + 16;
        bf16x8 a1 = *(const bf16x8*)&sxs[((rA1)     * DD + k0) ^ ((rA1 & 7) << 3)];
        #pragma unroll
        for (int nc = 0; nc < 4; nc++) {
            bf16x8 b = *(const bf16x8*)&packB1[(((wc * 4 + nc) * 4 + kt) * 64 + lane) * 8];
            acc[0][nc] = __builtin_amdgcn_mfma_f32_16x16x32_bf16(a0, b, acc[0][nc], 0, 0, 0);
            acc[1][nc] = __builtin_amdgcn_mfma_f32_16x16x32_bf16(a1, b, acc[1][nc], 0, 0, 0);
        }
    }
    __syncthreads();

    {
        float bias1[4];
        #pragma unroll
        for (int nc = 0; nc < 4; nc++) bias1[nc] = p1b[wc * 64 + nc * 16 + (lane & 15)];
        #pragma unroll
        for (int mrf = 0; mrf < 2; mrf++) {
            int rbase = wr * 32 + mrf * 16 + (lane >> 4) * 4;
            #pragma unroll
            for (int nc = 0; nc < 4; nc++) {
                int col = wc * 64 + nc * 16 + (lane & 15);
                #pragma unroll
                for (int j = 0; j < 4; j++) {
                    float h = acc[mrf][nc][j] + bias1[nc];
                    h = h / (1.f + __expf(-h));
                    int rr = rbase + j;
                    sxs[(rr * DD + col) ^ ((rr & 7) << 3)] = f2bf(h);
                }
            }
        }
    }
    __syncthreads();

    f32x4 acc2[2][4];
    #pragma unroll
    for (int i = 0; i < 2; i++)
        #pragma unroll
        for (int j = 0; j < 4; j++) acc2[i][j] = (f32x4){0.f, 0.f, 0.f, 0.f};

    #pragma unroll
    for (int kt = 0; kt < 4; kt++) {
        int k0 = kt * 32 + kb;
        bf16x8 a0 = *(const bf16x8*)&sxs[((rA)      * DD + k0) ^ ((rA & 7) << 3)];
        int rA1 = rA + 16;
        bf16x8 a1 = *(const bf16x8*)&sxs[((rA1)     * DD + k0) ^ ((rA1 & 7) << 3)];
        #pragma unroll
        for (int nc = 0; nc < 4; nc++) {
            bf16x8 b = *(const bf16x8*)&packB2[(((wc * 4 + nc) * 4 + kt) * 64 + lane) * 8];
            acc2[0][nc] = __builtin_amdgcn_mfma_f32_16x16x32_bf16(a0, b, acc2[0][nc], 0, 0, 0);
            acc2[1][nc] = __builtin_amdgcn_mfma_f32_16x16x32_bf16(a1, b, acc2[1][nc], 0, 0, 0);
        }
    }
    __syncthreads();

    float bias2[4];
    #pragma unroll
    for (int nc = 0; nc < 4; nc++) bias2[nc] = p2b[wc * 64 + nc * 16 + (lane & 15)];

    #pragma unroll
    for (int half = 0; half < 2; half++) {
        if (wr == half) {
            #pragma unroll
            for (int mrf = 0; mrf < 2; mrf++) {
                int rloc = mrf * 16 + (lane >> 4) * 4;
                #pragma unroll
                for (int nc = 0; nc < 4; nc++) {
                    int col = wc * 64 + nc * 16 + (lane & 15);
                    #pragma unroll
                    for (int j = 0; j < 4; j++)
                        outS[(rloc + j) * DD + col] = acc2[mrf][nc][j] + bias2[nc];
                }
            }
        }
        __syncthreads();
        {
            int col = tid & 127;
            int r0 = (tid >> 7) * 16;
            float racc = 0.f;
            int cseg = -1;
            for (int r = r0; r < r0 + 16; r++) {
                int seg = segS[half * 32 + r];
                if (seg != cseg) {
                    if (cseg >= 0) atomicAdd(&accum[(size_t)cseg * DD + col], racc);
                    racc = 0.f; cseg = seg;
                }
                if (seg >= 0) racc += outS[r * DD + col];
            }
            if (cseg >= 0) atomicAdd(&accum[(size_t)cseg * DD + col], racc);
        }
        __syncthreads();
    }
}

// ---------------- final combine: LN + SiLU ----------------
__global__ __launch_bounds__(128) void final_kernel(
    const float* __restrict__ pre, const float* __restrict__ accum, const int* __restrict__ cnt,
    const float* __restrict__ on_g, const float* __restrict__ on_b,
    float* __restrict__ out, int N)
{
    __shared__ float red[4];
    int tid = threadIdx.x;
    int n = blockIdx.x;
    float inv = 1.f / fmaxf((float)cnt[n], 1.f);
    size_t o = (size_t)n * DD + tid;
    float val = pre[o] + accum[o] * inv;
    float s1 = val, s2 = val * val;
    for (int off = 32; off >= 1; off >>= 1) { s1 += __shfl_xor(s1, off); s2 += __shfl_xor(s2, off); }
    int w = tid >> 6;
    if ((tid & 63) == 0) { red[2 * w] = s1; red[2 * w + 1] = s2; }
    __syncthreads();
    float mean = (red[0] + red[2]) * (1.f / DD);
    float var  = (red[1] + red[3]) * (1.f / DD) - mean * mean;
    float ov = (val - mean) * rsqrtf(var + 1e-5f) * on_g[tid] + on_b[tid];
    out[o] = ov / (1.f + __expf(-ov));
}

extern "C" void kernel_launch(void* const* d_in, const int* in_sizes, int n_in,
                              void* d_out, int out_size, void* d_ws, size_t ws_size,
                              hipStream_t stream)
{
    const float* x         = (const float*)d_in[0];
    const int*   edge_index= (const int*)  d_in[1];
    const float* edge_attr = (const float*)d_in[2];
    const int*   sub_nodes = (const int*)  d_in[3];
    const int*   sub_ind   = (const int*)  d_in[4];
    const float* Wq = (const float*)d_in[5];  const float* bq = (const float*)d_in[6];
    const float* Wk = (const float*)d_in[7];  const float* bk = (const float*)d_in[8];
    const float* Wv = (const float*)d_in[9];  const float* bv = (const float*)d_in[10];
    const float* We = (const float*)d_in[11]; const float* be = (const float*)d_in[12];
    const float* Ws = (const float*)d_in[13]; const float* bs = (const float*)d_in[14];
    const float* sn_g = (const float*)d_in[15]; const float* sn_b = (const float*)d_in[16];
    const float* p1w = (const float*)d_in[17]; const float* p1b = (const float*)d_in[18];
    const float* p2w = (const float*)d_in[19]; const float* p2b = (const float*)d_in[20];
    const float* on_g = (const float*)d_in[21]; const float* on_b = (const float*)d_in[22];

    int N = in_sizes[0] / DD;
    int E = in_sizes[1] / 2;
    int M = in_sizes[3];
    float* out = (float*)d_out;

    unsigned short* packB1 = (unsigned short*)d_ws;
    unsigned short* packB2 = packB1 + DD * DD;
    size_t ND = (size_t)N * DD;
    float* q     = (float*)(packB2 + DD * DD);
    float* k     = q + ND;
    float* v     = k + ND;
    float* pre   = v + ND;
    float* accum = pre + ND;
    int* indptr  = (int*)(accum + ND);   // N+1
    int* fill    = indptr + (N + 1);     // N
    int* deg     = fill + N;             // N
    int* cnt     = deg + N;              // N
    int* sindptr = cnt + N;              // N+1
    int* sfill   = sindptr + (N + 1);    // N
    int* ssrc    = sfill + N;            // E
    int* seid    = ssrc + E;             // E
    int* snode   = seid + E;             // M
    int* sseg    = snode + M;            // M

    const int* srcA = edge_index;
    const int* dstA = edge_index + E;

    hipMemsetAsync(deg, 0, (size_t)N * sizeof(int), stream);
    hipMemsetAsync(cnt, 0, (size_t)N * sizeof(int), stream);
    hipMemsetAsync(accum, 0, ND * sizeof(float), stream);

    packw_kernel<<<(DD * DD + 255) / 256, 256, 0, stream>>>(p1w, packB1);
    packw_kernel<<<(DD * DD + 255) / 256, 256, 0, stream>>>(p2w, packB2);

    lin4_kernel<<<(N + 3) / 4, 128, 0, stream>>>(x, Wq, bq, Wk, bk, Wv, bv, Ws, bs, q, k, v, pre, N);
    count_kernel<<<2048, 256, 0, stream>>>(dstA, E, deg);
    count_kernel<<<2048, 256, 0, stream>>>(sub_ind, M, cnt);
    scan_kernel<<<1, 1024, 0, stream>>>(deg, N, indptr, fill);
    escatter_kernel<<<2048, 256, 0, stream>>>(srcA, dstA, E, fill, ssrc, seid);
    scan_kernel<<<1, 1024, 0, stream>>>(cnt, N, sindptr, sfill);
    sscatter_kernel<<<2048, 256, 0, stream>>>(sub_nodes, sub_ind, M, sfill, snode, sseg);
    attn_kernel<<<(N + 7) / 8, 512, 0, stream>>>(q, k, v, edge_attr, We, be, indptr, ssrc, seid, pre, N);
    submlp_mfma_kernel<<<(M + 63) / 64, 256, 0, stream>>>(x, snode, sseg, sn_g, sn_b,
                                                          packB1, p1b, packB2, p2b, accum, M);
    final_kernel<<<N, 128, 0, stream>>>(pre, accum, cnt, on_g, on_b, out, N);
}

// Round 6
// 1226.316 us; speedup vs baseline: 1.0109x; 1.0109x over previous
//
#include <hip/hip_runtime.h>
#include <math.h>

#define DD 128
#define EDD 64

typedef __attribute__((ext_vector_type(8))) short bf16x8;
typedef __attribute__((ext_vector_type(4))) float f32x4;

__device__ inline unsigned short f2bf(float f) {
    unsigned int u = __float_as_uint(f);
    u += 0x7FFFu + ((u >> 16) & 1u);
    return (unsigned short)(u >> 16);
}
__device__ inline unsigned int pack2bf16(float lo, float hi) {
    return (unsigned int)f2bf(lo) | ((unsigned int)f2bf(hi) << 16);
}

// ---------------- fused q/k/v/skip linears: 4 rows per 128-thread block ----------------
__global__ __launch_bounds__(128) void lin4_kernel(
    const float* __restrict__ x,
    const float* __restrict__ Wq, const float* __restrict__ bq,
    const float* __restrict__ Wk, const float* __restrict__ bk,
    const float* __restrict__ Wv, const float* __restrict__ bv,
    const float* __restrict__ Ws, const float* __restrict__ bs,
    float* __restrict__ q, float* __restrict__ k, float* __restrict__ v,
    float* __restrict__ pre, int N)
{
    __shared__ float xs[4][DD];
    int tid = threadIdx.x;
    int r0 = blockIdx.x * 4;
    for (int r = 0; r < 4; r++) {
        int row = r0 + r;
        xs[r][tid] = (row < N) ? x[(size_t)row * DD + tid] : 0.f;
    }
    __syncthreads();
    float aq[4], ak[4], av[4], as_[4];
    float bqv = bq[tid], bkv = bk[tid], bvv = bv[tid], bsv = bs[tid];
    #pragma unroll
    for (int r = 0; r < 4; r++) { aq[r] = bqv; ak[r] = bkv; av[r] = bvv; as_[r] = bsv; }
    for (int kk = 0; kk < DD; kk++) {
        float wq = Wq[kk * DD + tid], wk = Wk[kk * DD + tid];
        float wv = Wv[kk * DD + tid], ws = Ws[kk * DD + tid];
        #pragma unroll
        for (int r = 0; r < 4; r++) {
            float xv = xs[r][kk];
            aq[r] += xv * wq; ak[r] += xv * wk; av[r] += xv * wv; as_[r] += xv * ws;
        }
    }
    for (int r = 0; r < 4; r++) {
        int row = r0 + r;
        if (row >= N) break;
        size_t o = (size_t)row * DD + tid;
        q[o] = aq[r]; k[o] = ak[r]; v[o] = av[r];
        pre[o] = xs[r][tid] + as_[r];   // x + (x@Ws + bs)
    }
}

// ---------------- histogram ----------------
__global__ void count_kernel(const int* __restrict__ idx, int n, int* __restrict__ cnt)
{
    int i = blockIdx.x * blockDim.x + threadIdx.x;
    int stride = gridDim.x * blockDim.x;
    for (; i < n; i += stride) atomicAdd(&cnt[idx[i]], 1);
}

// ---------------- single-block exclusive scan ----------------
__global__ __launch_bounds__(1024) void scan_kernel(const int* __restrict__ deg, int N,
                                                    int* __restrict__ indptr, int* __restrict__ fill)
{
    __shared__ int s[1024];
    int tid = threadIdx.x;
    int running = 0;
    for (int base = 0; base < N; base += 1024) {
        int i = base + tid;
        int val = (i < N) ? deg[i] : 0;
        s[tid] = val; __syncthreads();
        for (int off = 1; off < 1024; off <<= 1) {
            int t = (tid >= off) ? s[tid - off] : 0;
            __syncthreads();
            s[tid] += t;
            __syncthreads();
        }
        int excl = s[tid] - val;
        if (i < N) { indptr[i] = running + excl; fill[i] = running + excl; }
        int tot = s[1023];
        __syncthreads();
        running += tot;
    }
    if (tid == 0) indptr[N] = running;
}

// ---------------- scatter edge ids into dst-CSR ----------------
__global__ void escatter_kernel(const int* __restrict__ srcA, const int* __restrict__ dstA, int E,
                                int* __restrict__ fill, int* __restrict__ ssrc, int* __restrict__ seid)
{
    int i = blockIdx.x * blockDim.x + threadIdx.x;
    int stride = gridDim.x * blockDim.x;
    for (; i < E; i += stride) {
        int d = dstA[i];
        int pos = atomicAdd(&fill[d], 1);
        ssrc[pos] = srcA[i];
        seid[pos] = i;
    }
}

// ---------------- scatter subgraph rows into segment-sorted order ----------------
__global__ void sscatter_kernel(const int* __restrict__ sub_nodes, const int* __restrict__ sub_ind,
                                int M, int* __restrict__ sfill,
                                int* __restrict__ snode, int* __restrict__ sseg)
{
    int i = blockIdx.x * blockDim.x + threadIdx.x;
    int stride = gridDim.x * blockDim.x;
    for (; i < M; i += stride) {
        int seg = sub_ind[i];
        int pos = atomicAdd(&sfill[seg], 1);
        snode[pos] = sub_nodes[i];
        sseg[pos] = seg;
    }
}

// ---------------- attention v5: lane owns contiguous j-octet -> no bpermute in edge loop ----------------
// Lane L: head g=L>>3, jj=L&7, owns j in {8jj..8jj+7}, channels c0=2L,2L+1 (head g: lanes 8g..8g+7).
// alpha[h] = (q.k[src] + sum_j ea[j]*qWe[j][h] + q.be)/4. ea loaded as 2x float4 directly.
// Value-side e deferred: aea[r] += p*ea[8jj+r]; apply We once per node in epilogue.
__device__ inline int rowbase(int c) { return c * 65 + ((c >> 4) << 2); }   // bank-spread row base

__global__ __launch_bounds__(512, 8) void attn_kernel(
    const float* __restrict__ q, const float* __restrict__ k, const float* __restrict__ v,
    const float* __restrict__ edge_attr, const float* __restrict__ We, const float* __restrict__ be,
    const int* __restrict__ indptr, const int* __restrict__ ssrc, const int* __restrict__ seid,
    float* __restrict__ pre, int N)
{
    __shared__ float WeT[DD * 65 + 32];   // WeT[rowbase(c) + j] = We[j*128 + c]
    int tid = threadIdx.x;
    for (int idx = tid; idx < EDD * DD; idx += 512) {
        int j = idx >> 7, c = idx & 127;
        WeT[rowbase(c) + j] = We[idx];
    }
    __syncthreads();

    int wave = tid >> 6, lane = tid & 63;
    int n = blockIdx.x * 8 + wave;
    if (n >= N) return;

    int jj = lane & 7;
    int gbase = lane & 56;
    int c0 = lane * 2;

    float2 qv  = *(const float2*)&q[(size_t)n * DD + c0];
    float2 bev = *(const float2*)&be[c0];

    // qbe4 = (q . be)/4, uniform per head group
    float t = qv.x * bev.x + qv.y * bev.y;
    t += __shfl_xor(t, 1); t += __shfl_xor(t, 2); t += __shfl_xor(t, 4);
    float qbe4 = t * 0.25f;

    // qWe[r] = sum_c q[n,16g+c] * We[8jj+r][16g+c]
    float qWe[8];
    #pragma unroll
    for (int r = 0; r < 8; r++) qWe[r] = 0.f;
    #pragma unroll
    for (int cc = 0; cc < 8; cc++) {
        float q0 = __shfl(qv.x, gbase + cc);
        float q1 = __shfl(qv.y, gbase + cc);
        const float* w0 = &WeT[rowbase((gbase << 1) + 2 * cc) + 8 * jj];
        const float* w1 = &WeT[rowbase((gbase << 1) + 2 * cc + 1) + 8 * jj];
        #pragma unroll
        for (int r = 0; r < 8; r++)
            qWe[r] += q0 * w0[r] + q1 * w1[r];
    }

    int start = indptr[n], end = indptr[n + 1];
    float s = 0.f, av0 = 0.f, av1 = 0.f;
    float aea[8];
    #pragma unroll
    for (int r = 0; r < 8; r++) aea[r] = 0.f;

    for (int ii = start; ii < end; ii++) {
        int src = ssrc[ii];
        int eid = seid[ii];
        const float4* eap = (const float4*)&edge_attr[(size_t)eid * EDD + 8 * jj];
        float4 ea0 = eap[0];
        float4 ea1 = eap[1];
        float2 kv = *(const float2*)&k[(size_t)src * DD + c0];
        float2 vv = *(const float2*)&v[(size_t)src * DD + c0];
        float part = qv.x * kv.x + qv.y * kv.y;
        part += ea0.x * qWe[0] + ea0.y * qWe[1] + ea0.z * qWe[2] + ea0.w * qWe[3];
        part += ea1.x * qWe[4] + ea1.y * qWe[5] + ea1.z * qWe[6] + ea1.w * qWe[7];
        part += __shfl_xor(part, 1);
        part += __shfl_xor(part, 2);
        part += __shfl_xor(part, 4);
        float p = __expf(part * 0.25f + qbe4);   // exact softmax numerator (alpha O(1)-bounded)
        s += p;
        av0 += p * vv.x;
        av1 += p * vv.y;
        aea[0] += p * ea0.x; aea[1] += p * ea0.y; aea[2] += p * ea0.z; aea[3] += p * ea0.w;
        aea[4] += p * ea1.x; aea[5] += p * ea1.y; aea[6] += p * ea1.z; aea[7] += p * ea1.w;
    }

    if (end > start) {
        float inv = 1.f / s;
        // oe[c] = sum_j aea_full[g][j] * We[j][c]; aea_full[g][8m+r] lives in lane gbase+m reg r
        float oe0 = 0.f, oe1 = 0.f;
        const float* wr0 = &WeT[rowbase(c0)];
        const float* wr1 = &WeT[rowbase(c0 + 1)];
        #pragma unroll
        for (int m = 0; m < 8; m++) {
            #pragma unroll
            for (int r = 0; r < 8; r++) {
                float a = __shfl(aea[r], gbase + m);
                oe0 += a * wr0[8 * m + r];
                oe1 += a * wr1[8 * m + r];
            }
        }
        size_t o = (size_t)n * DD + c0;
        pre[o]     += (av0 + oe0) * inv + bev.x;
        pre[o + 1] += (av1 + oe1) * inv + bev.y;
    }
}

// ---------------- pack a [128][128] fp32 weight into bf16 MFMA B-fragment order ----------------
__global__ __launch_bounds__(256) void packw_kernel(const float* __restrict__ w,
                                                    unsigned short* __restrict__ packed)
{
    int idx = blockIdx.x * 256 + threadIdx.x;
    if (idx >= DD * DD) return;
    int j    = idx & 7;
    int lane = (idx >> 3) & 63;
    int kt   = (idx >> 9) & 3;
    int ncf  = idx >> 11;
    int kk  = kt * 32 + (lane >> 4) * 8 + j;
    int col = ncf * 16 + (lane & 15);
    packed[idx] = f2bf(w[kk * DD + col]);
}

// ---------------- subgraph branch: segment-sorted, in-place LDS, run-length reduced atomics ----------------
__global__ __launch_bounds__(256, 8) void submlp_mfma_kernel(
    const float* __restrict__ x, const int* __restrict__ snode, const int* __restrict__ sseg,
    const float* __restrict__ sn_g, const float* __restrict__ sn_b,
    const unsigned short* __restrict__ packB1, const float* __restrict__ p1b,
    const unsigned short* __restrict__ packB2, const float* __restrict__ p2b,
    float* __restrict__ accum, int M)
{
    __shared__ unsigned short sxs[64 * DD];   // 16 KB; reused in-place for hs, then fp32 out half-tile
    __shared__ int segS[64];
    float* outS = (float*)sxs;

    int tid = threadIdx.x;
    int lane = tid & 63, wid = tid >> 6;
    size_t m0 = (size_t)blockIdx.x * 64;

    if (tid < 64) {
        size_t row = m0 + tid;
        segS[tid] = (row < (size_t)M) ? sseg[row] : -1;
    }

    {
        int nid = 0;
        {
            size_t row = m0 + wid * 16 + (lane & 15);
            if (lane < 16 && row < (size_t)M) nid = snode[row];
        }
        float g0 = sn_g[2 * lane], g1 = sn_g[2 * lane + 1];
        float b0 = sn_b[2 * lane], b1 = sn_b[2 * lane + 1];
        #pragma unroll
        for (int r = 0; r < 16; r++) {
            int tr = wid * 16 + r;
            size_t row = m0 + tr;
            int node = __shfl(nid, r);
            float v0 = 0.f, v1 = 0.f;
            if (row < (size_t)M) {
                float2 xv = *(const float2*)&x[(size_t)node * DD + 2 * lane];
                v0 = xv.x; v1 = xv.y;
            }
            float s1 = v0 + v1, s2 = v0 * v0 + v1 * v1;
            #pragma unroll
            for (int o = 32; o >= 1; o >>= 1) { s1 += __shfl_xor(s1, o); s2 += __shfl_xor(s2, o); }
            float mean = s1 * (1.f / DD);
            float var  = s2 * (1.f / DD) - mean * mean;
            float rs = rsqrtf(var + 1e-5f);
            float n0 = (v0 - mean) * rs * g0 + b0;
            float n1 = (v1 - mean) * rs * g1 + b1;
            unsigned int uidx = ((unsigned)(tr * 64 + lane)) ^ (((unsigned)tr & 7u) << 2);
            ((unsigned int*)sxs)[uidx] = pack2bf16(n0, n1);
        }
    }
    __syncthreads();

    int wr = wid >> 1, wc = wid & 1;
    int rA = wr * 32 + (lane & 15);
    int kb = (lane >> 4) * 8;

    f32x4 acc[2][4];
    #pragma unroll
    for (int i = 0; i < 2; i++)
        #pragma unroll
        for (int j = 0; j < 4; j++) acc[i][j] = (f32x4){0.f, 0.f, 0.f, 0.f};

    #pragma unroll
    for (int kt = 0; kt < 4; kt++) {
        int k0 = kt * 32 + kb;
        bf16x8 a0 = *(const bf16x8*)&sxs[((rA)      * DD + k0) ^ ((rA & 7) << 3)];
        int rA1 = rA + 16;
        bf16x8 a1 = *(const bf16x8*)&sxs[((rA1)     * DD + k0) ^ ((rA1 & 7) << 3)];
        #pragma unroll
        for (int nc = 0; nc < 4; nc++) {
            bf16x8 b = *(const bf16x8*)&packB1[(((wc * 4 + nc) * 4 + kt) * 64 + lane) * 8];
            acc[0][nc] = __builtin_amdgcn_mfma_f32_16x16x32_bf16(a0, b, acc[0][nc], 0, 0, 0);
            acc[1][nc] = __builtin_amdgcn_mfma_f32_16x16x32_bf16(a1, b, acc[1][nc], 0, 0, 0);
        }
    }
    __syncthreads();

    {
        float bias1[4];
        #pragma unroll
        for (int nc = 0; nc < 4; nc++) bias1[nc] = p1b[wc * 64 + nc * 16 + (lane & 15)];
        #pragma unroll
        for (int mrf = 0; mrf < 2; mrf++) {
            int rbase = wr * 32 + mrf * 16 + (lane >> 4) * 4;
            #pragma unroll
            for (int nc = 0; nc < 4; nc++) {
                int col = wc * 64 + nc * 16 + (lane & 15);
                #pragma unroll
                for (int j = 0; j < 4; j++) {
                    float h = acc[mrf][nc][j] + bias1[nc];
                    h = h / (1.f + __expf(-h));
                    int rr = rbase + j;
                    sxs[(rr * DD + col) ^ ((rr & 7) << 3)] = f2bf(h);
                }
            }
        }
    }
    __syncthreads();

    f32x4 acc2[2][4];
    #pragma unroll
    for (int i = 0; i < 2; i++)
        #pragma unroll
        for (int j = 0; j < 4; j++) acc2[i][j] = (f32x4){0.f, 0.f, 0.f, 0.f};

    #pragma unroll
    for (int kt = 0; kt < 4; kt++) {
        int k0 = kt * 32 + kb;
        bf16x8 a0 = *(const bf16x8*)&sxs[((rA)      * DD + k0) ^ ((rA & 7) << 3)];
        int rA1 = rA + 16;
        bf16x8 a1 = *(const bf16x8*)&sxs[((rA1)     * DD + k0) ^ ((rA1 & 7) << 3)];
        #pragma unroll
        for (int nc = 0; nc < 4; nc++) {
            bf16x8 b = *(const bf16x8*)&packB2[(((wc * 4 + nc) * 4 + kt) * 64 + lane) * 8];
            acc2[0][nc] = __builtin_amdgcn_mfma_f32_16x16x32_bf16(a0, b, acc2[0][nc], 0, 0, 0);
            acc2[1][nc] = __builtin_amdgcn_mfma_f32_16x16x32_bf16(a1, b, acc2[1][nc], 0, 0, 0);
        }
    }
    __syncthreads();

    float bias2[4];
    #pragma unroll
    for (int nc = 0; nc < 4; nc++) bias2[nc] = p2b[wc * 64 + nc * 16 + (lane & 15)];

    #pragma unroll
    for (int half = 0; half < 2; half++) {
        if (wr == half) {
            #pragma unroll
            for (int mrf = 0; mrf < 2; mrf++) {
                int rloc = mrf * 16 + (lane >> 4) * 4;
                #pragma unroll
                for (int nc = 0; nc < 4; nc++) {
                    int col = wc * 64 + nc * 16 + (lane & 15);
                    #pragma unroll
                    for (int j = 0; j < 4; j++)
                        outS[(rloc + j) * DD + col] = acc2[mrf][nc][j] + bias2[nc];
                }
            }
        }
        __syncthreads();
        {
            int col = tid & 127;
            int r0 = (tid >> 7) * 16;
            float racc = 0.f;
            int cseg = -1;
            for (int r = r0; r < r0 + 16; r++) {
                int seg = segS[half * 32 + r];
                if (seg != cseg) {
                    if (cseg >= 0) atomicAdd(&accum[(size_t)cseg * DD + col], racc);
                    racc = 0.f; cseg = seg;
                }
                if (seg >= 0) racc += outS[r * DD + col];
            }
            if (cseg >= 0) atomicAdd(&accum[(size_t)cseg * DD + col], racc);
        }
        __syncthreads();
    }
}

// ---------------- final combine: LN + SiLU ----------------
__global__ __launch_bounds__(128) void final_kernel(
    const float* __restrict__ pre, const float* __restrict__ accum, const int* __restrict__ cnt,
    const float* __restrict__ on_g, const float* __restrict__ on_b,
    float* __restrict__ out, int N)
{
    __shared__ float red[4];
    int tid = threadIdx.x;
    int n = blockIdx.x;
    float inv = 1.f / fmaxf((float)cnt[n], 1.f);
    size_t o = (size_t)n * DD + tid;
    float val = pre[o] + accum[o] * inv;
    float s1 = val, s2 = val * val;
    for (int off = 32; off >= 1; off >>= 1) { s1 += __shfl_xor(s1, off); s2 += __shfl_xor(s2, off); }
    int w = tid >> 6;
    if ((tid & 63) == 0) { red[2 * w] = s1; red[2 * w + 1] = s2; }
    __syncthreads();
    float mean = (red[0] + red[2]) * (1.f / DD);
    float var  = (red[1] + red[3]) * (1.f / DD) - mean * mean;
    float ov = (val - mean) * rsqrtf(var + 1e-5f) * on_g[tid] + on_b[tid];
    out[o] = ov / (1.f + __expf(-ov));
}

extern "C" void kernel_launch(void* const* d_in, const int* in_sizes, int n_in,
                              void* d_out, int out_size, void* d_ws, size_t ws_size,
                              hipStream_t stream)
{
    const float* x         = (const float*)d_in[0];
    const int*   edge_index= (const int*)  d_in[1];
    const float* edge_attr = (const float*)d_in[2];
    const int*   sub_nodes = (const int*)  d_in[3];
    const int*   sub_ind   = (const int*)  d_in[4];
    const float* Wq = (const float*)d_in[5];  const float* bq = (const float*)d_in[6];
    const float* Wk = (const float*)d_in[7];  const float* bk = (const float*)d_in[8];
    const float* Wv = (const float*)d_in[9];  const float* bv = (const float*)d_in[10];
    const float* We = (const float*)d_in[11]; const float* be = (const float*)d_in[12];
    const float* Ws = (const float*)d_in[13]; const float* bs = (const float*)d_in[14];
    const float* sn_g = (const float*)d_in[15]; const float* sn_b = (const float*)d_in[16];
    const float* p1w = (const float*)d_in[17]; const float* p1b = (const float*)d_in[18];
    const float* p2w = (const float*)d_in[19]; const float* p2b = (const float*)d_in[20];
    const float* on_g = (const float*)d_in[21]; const float* on_b = (const float*)d_in[22];

    int N = in_sizes[0] / DD;
    int E = in_sizes[1] / 2;
    int M = in_sizes[3];
    float* out = (float*)d_out;

    unsigned short* packB1 = (unsigned short*)d_ws;
    unsigned short* packB2 = packB1 + DD * DD;
    size_t ND = (size_t)N * DD;
    float* q     = (float*)(packB2 + DD * DD);
    float* k     = q + ND;
    float* v     = k + ND;
    float* pre   = v + ND;
    float* accum = pre + ND;
    int* indptr  = (int*)(accum + ND);   // N+1
    int* fill    = indptr + (N + 1);     // N
    int* deg     = fill + N;             // N
    int* cnt     = deg + N;              // N
    int* sindptr = cnt + N;              // N+1
    int* sfill   = sindptr + (N + 1);    // N
    int* ssrc    = sfill + N;            // E
    int* seid    = ssrc + E;             // E
    int* snode   = seid + E;             // M
    int* sseg    = snode + M;            // M

    const int* srcA = edge_index;
    const int* dstA = edge_index + E;

    hipMemsetAsync(deg, 0, (size_t)N * sizeof(int), stream);
    hipMemsetAsync(cnt, 0, (size_t)N * sizeof(int), stream);
    hipMemsetAsync(accum, 0, ND * sizeof(float), stream);

    packw_kernel<<<(DD * DD + 255) / 256, 256, 0, stream>>>(p1w, packB1);
    packw_kernel<<<(DD * DD + 255) / 256, 256, 0, stream>>>(p2w, packB2);

    lin4_kernel<<<(N + 3) / 4, 128, 0, stream>>>(x, Wq, bq, Wk, bk, Wv, bv, Ws, bs, q, k, v, pre, N);
    count_kernel<<<2048, 256, 0, stream>>>(dstA, E, deg);
    count_kernel<<<2048, 256, 0, stream>>>(sub_ind, M, cnt);
    scan_kernel<<<1, 1024, 0, stream>>>(deg, N, indptr, fill);
    escatter_kernel<<<2048, 256, 0, stream>>>(srcA, dstA, E, fill, ssrc, seid);
    scan_kernel<<<1, 1024, 0, stream>>>(cnt, N, sindptr, sfill);
    sscatter_kernel<<<2048, 256, 0, stream>>>(sub_nodes, sub_ind, M, sfill, snode, sseg);
    attn_kernel<<<(N + 7) / 8, 512, 0, stream>>>(q, k, v, edge_attr, We, be, indptr, ssrc, seid, pre, N);
    submlp_mfma_kernel<<<(M + 63) / 64, 256, 0, stream>>>(x, snode, sseg, sn_g, sn_b,
                                                          packB1, p1b, packB2, p2b, accum, M);
    final_kernel<<<N, 128, 0, stream>>>(pre, accum, cnt, on_g, on_b, out, N);
}

// Round 7
// 1181.300 us; speedup vs baseline: 1.0494x; 1.0381x over previous
//
#include <hip/hip_runtime.h>
#include <math.h>

#define DD 128
#define EDD 64

typedef __attribute__((ext_vector_type(8))) short bf16x8;
typedef __attribute__((ext_vector_type(4))) float f32x4;

__device__ inline unsigned short f2bf(float f) {
    unsigned int u = __float_as_uint(f);
    u += 0x7FFFu + ((u >> 16) & 1u);
    return (unsigned short)(u >> 16);
}
__device__ inline unsigned int pack2bf16(float lo, float hi) {
    return (unsigned int)f2bf(lo) | ((unsigned int)f2bf(hi) << 16);
}

// ---------------- fused q/k/v/skip linears: 4 rows per 128-thread block ----------------
// Outputs: q (row-major), kv interleaved (slot L = [k(2L),k(2L+1),v(2L),v(2L+1)]), pre = x + x@Ws+bs
__global__ __launch_bounds__(128) void lin4_kernel(
    const float* __restrict__ x,
    const float* __restrict__ Wq, const float* __restrict__ bq,
    const float* __restrict__ Wk, const float* __restrict__ bk,
    const float* __restrict__ Wv, const float* __restrict__ bv,
    const float* __restrict__ Ws, const float* __restrict__ bs,
    float* __restrict__ q, float* __restrict__ kvbuf,
    float* __restrict__ pre, int N)
{
    __shared__ float xs[4][DD];
    int tid = threadIdx.x;
    int r0 = blockIdx.x * 4;
    for (int r = 0; r < 4; r++) {
        int row = r0 + r;
        xs[r][tid] = (row < N) ? x[(size_t)row * DD + tid] : 0.f;
    }
    __syncthreads();
    float aq[4], ak[4], av[4], as_[4];
    float bqv = bq[tid], bkv = bk[tid], bvv = bv[tid], bsv = bs[tid];
    #pragma unroll
    for (int r = 0; r < 4; r++) { aq[r] = bqv; ak[r] = bkv; av[r] = bvv; as_[r] = bsv; }
    for (int kk = 0; kk < DD; kk++) {
        float wq = Wq[kk * DD + tid], wk = Wk[kk * DD + tid];
        float wv = Wv[kk * DD + tid], ws = Ws[kk * DD + tid];
        #pragma unroll
        for (int r = 0; r < 4; r++) {
            float xv = xs[r][kk];
            aq[r] += xv * wq; ak[r] += xv * wk; av[r] += xv * wv; as_[r] += xv * ws;
        }
    }
    int slotbase = (tid >> 1) * 4 + (tid & 1);
    for (int r = 0; r < 4; r++) {
        int row = r0 + r;
        if (row >= N) break;
        size_t o = (size_t)row * DD + tid;
        q[o] = aq[r];
        pre[o] = xs[r][tid] + as_[r];
        size_t kb = (size_t)row * 256 + slotbase;
        kvbuf[kb]     = ak[r];
        kvbuf[kb + 2] = av[r];
    }
}

// ---------------- histogram ----------------
__global__ void count_kernel(const int* __restrict__ idx, int n, int* __restrict__ cnt)
{
    int i = blockIdx.x * blockDim.x + threadIdx.x;
    int stride = gridDim.x * blockDim.x;
    for (; i < n; i += stride) atomicAdd(&cnt[idx[i]], 1);
}

// ---------------- single-block exclusive scan ----------------
__global__ __launch_bounds__(1024) void scan_kernel(const int* __restrict__ deg, int N,
                                                    int* __restrict__ indptr, int* __restrict__ fill)
{
    __shared__ int s[1024];
    int tid = threadIdx.x;
    int running = 0;
    for (int base = 0; base < N; base += 1024) {
        int i = base + tid;
        int val = (i < N) ? deg[i] : 0;
        s[tid] = val; __syncthreads();
        for (int off = 1; off < 1024; off <<= 1) {
            int t = (tid >= off) ? s[tid - off] : 0;
            __syncthreads();
            s[tid] += t;
            __syncthreads();
        }
        int excl = s[tid] - val;
        if (i < N) { indptr[i] = running + excl; fill[i] = running + excl; }
        int tot = s[1023];
        __syncthreads();
        running += tot;
    }
    if (tid == 0) indptr[N] = running;
}

// ---------------- scatter edge (src,eid) pairs into dst-CSR ----------------
__global__ void escatter_kernel(const int* __restrict__ srcA, const int* __restrict__ dstA, int E,
                                int* __restrict__ fill, int2* __restrict__ spair)
{
    int i = blockIdx.x * blockDim.x + threadIdx.x;
    int stride = gridDim.x * blockDim.x;
    for (; i < E; i += stride) {
        int d = dstA[i];
        int pos = atomicAdd(&fill[d], 1);
        spair[pos] = make_int2(srcA[i], i);
    }
}

// ---------------- scatter subgraph rows into segment-sorted order ----------------
__global__ void sscatter_kernel(const int* __restrict__ sub_nodes, const int* __restrict__ sub_ind,
                                int M, int* __restrict__ sfill,
                                int* __restrict__ snode, int* __restrict__ sseg)
{
    int i = blockIdx.x * blockDim.x + threadIdx.x;
    int stride = gridDim.x * blockDim.x;
    for (; i < M; i += stride) {
        int seg = sub_ind[i];
        int pos = atomicAdd(&sfill[seg], 1);
        snode[pos] = sub_nodes[i];
        sseg[pos] = seg;
    }
}

// ---------------- attention v6: contiguous j-octet per lane, conflict-free WeT, kv-interleaved ----------------
// Lane L: head g=L>>3, jj=L&7, owns j in {8jj..8jj+7}, channels c0=2L,2L+1.
// WeT layout: stride 96 + pad 4*((c>>4)&7): build and epilogue b128 reads tile the 8 bank-quads evenly.
__device__ inline int rowbase96(int c) { return c * 96 + (((c >> 4) & 7) << 2); }

__global__ __launch_bounds__(512, 6) void attn_kernel(
    const float* __restrict__ q, const float* __restrict__ kvbuf,
    const float* __restrict__ edge_attr, const float* __restrict__ We, const float* __restrict__ be,
    const int* __restrict__ indptr, const int2* __restrict__ spair,
    float* __restrict__ pre, int N)
{
    __shared__ float WeT[96 * DD + 32];   // WeT[rowbase96(c) + j] = We[j*128 + c]  (~49 KB)
    int tid = threadIdx.x;
    for (int idx = tid; idx < EDD * DD; idx += 512) {
        int j = idx >> 7, c = idx & 127;
        WeT[rowbase96(c) + j] = We[idx];
    }
    __syncthreads();

    int wave = tid >> 6, lane = tid & 63;
    int n = blockIdx.x * 8 + wave;
    if (n >= N) return;

    int jj = lane & 7;
    int gbase = lane & 56;
    int c0 = lane * 2;

    float2 qv  = *(const float2*)&q[(size_t)n * DD + c0];
    float2 bev = *(const float2*)&be[c0];

    // qbe4 = (q . be)/4, uniform per head group
    float t = qv.x * bev.x + qv.y * bev.y;
    t += __shfl_xor(t, 1); t += __shfl_xor(t, 2); t += __shfl_xor(t, 4);
    float qbe4 = t * 0.25f;

    // qWe[r] = sum_c q[n,16g+c] * We[8jj+r][16g+c]   (b128 reads, conflict-free)
    float qWe[8];
    #pragma unroll
    for (int r = 0; r < 8; r++) qWe[r] = 0.f;
    #pragma unroll
    for (int cc = 0; cc < 8; cc++) {
        int c = (gbase << 1) + 2 * cc;
        float q0 = __shfl(qv.x, gbase + cc);
        float q1 = __shfl(qv.y, gbase + cc);
        const float4* w0p = (const float4*)&WeT[rowbase96(c) + 8 * jj];
        const float4* w1p = (const float4*)&WeT[rowbase96(c + 1) + 8 * jj];
        float4 w0a = w0p[0], w0b = w0p[1];
        float4 w1a = w1p[0], w1b = w1p[1];
        qWe[0] += q0 * w0a.x + q1 * w1a.x;
        qWe[1] += q0 * w0a.y + q1 * w1a.y;
        qWe[2] += q0 * w0a.z + q1 * w1a.z;
        qWe[3] += q0 * w0a.w + q1 * w1a.w;
        qWe[4] += q0 * w0b.x + q1 * w1b.x;
        qWe[5] += q0 * w0b.y + q1 * w1b.y;
        qWe[6] += q0 * w0b.z + q1 * w1b.z;
        qWe[7] += q0 * w0b.w + q1 * w1b.w;
    }

    int start = indptr[n], end = indptr[n + 1];
    float s = 0.f, av0 = 0.f, av1 = 0.f;
    float aea[8];
    #pragma unroll
    for (int r = 0; r < 8; r++) aea[r] = 0.f;

    for (int ii = start; ii < end; ii++) {
        int2 se = spair[ii];
        const float4* eap = (const float4*)&edge_attr[(size_t)se.y * EDD + 8 * jj];
        float4 ea0 = eap[0];
        float4 ea1 = eap[1];
        float4 kv = *(const float4*)&kvbuf[(size_t)se.x * 256 + 4 * lane];
        float part = qv.x * kv.x + qv.y * kv.y;
        part += ea0.x * qWe[0] + ea0.y * qWe[1] + ea0.z * qWe[2] + ea0.w * qWe[3];
        part += ea1.x * qWe[4] + ea1.y * qWe[5] + ea1.z * qWe[6] + ea1.w * qWe[7];
        part += __shfl_xor(part, 1);
        part += __shfl_xor(part, 2);
        part += __shfl_xor(part, 4);
        float p = __expf(part * 0.25f + qbe4);   // exact softmax numerator (alpha O(1)-bounded)
        s += p;
        av0 += p * kv.z;
        av1 += p * kv.w;
        aea[0] += p * ea0.x; aea[1] += p * ea0.y; aea[2] += p * ea0.z; aea[3] += p * ea0.w;
        aea[4] += p * ea1.x; aea[5] += p * ea1.y; aea[6] += p * ea1.z; aea[7] += p * ea1.w;
    }

    if (end > start) {
        float inv = 1.f / s;
        // oe[c] = sum_j aea_full[g][j] * We[j][c]; aea_full[g][8m+r] lives in lane gbase+m reg r
        float oe0 = 0.f, oe1 = 0.f;
        const float4* wr0 = (const float4*)&WeT[rowbase96(c0)];
        const float4* wr1 = (const float4*)&WeT[rowbase96(c0 + 1)];
        #pragma unroll
        for (int m = 0; m < 8; m++) {
            float4 wA0 = wr0[2 * m], wA1 = wr0[2 * m + 1];
            float4 wB0 = wr1[2 * m], wB1 = wr1[2 * m + 1];
            float a0 = __shfl(aea[0], gbase + m);
            float a1 = __shfl(aea[1], gbase + m);
            float a2 = __shfl(aea[2], gbase + m);
            float a3 = __shfl(aea[3], gbase + m);
            float a4 = __shfl(aea[4], gbase + m);
            float a5 = __shfl(aea[5], gbase + m);
            float a6 = __shfl(aea[6], gbase + m);
            float a7 = __shfl(aea[7], gbase + m);
            oe0 += a0 * wA0.x + a1 * wA0.y + a2 * wA0.z + a3 * wA0.w
                 + a4 * wA1.x + a5 * wA1.y + a6 * wA1.z + a7 * wA1.w;
            oe1 += a0 * wB0.x + a1 * wB0.y + a2 * wB0.z + a3 * wB0.w
                 + a4 * wB1.x + a5 * wB1.y + a6 * wB1.z + a7 * wB1.w;
        }
        size_t o = (size_t)n * DD + c0;
        pre[o]     += (av0 + oe0) * inv + bev.x;
        pre[o + 1] += (av1 + oe1) * inv + bev.y;
    }
}

// ---------------- pack a [128][128] fp32 weight into bf16 MFMA B-fragment order ----------------
__global__ __launch_bounds__(256) void packw_kernel(const float* __restrict__ w,
                                                    unsigned short* __restrict__ packed)
{
    int idx = blockIdx.x * 256 + threadIdx.x;
    if (idx >= DD * DD) return;
    int j    = idx & 7;
    int lane = (idx >> 3) & 63;
    int kt   = (idx >> 9) & 3;
    int ncf  = idx >> 11;
    int kk  = kt * 32 + (lane >> 4) * 8 + j;
    int col = ncf * 16 + (lane & 15);
    packed[idx] = f2bf(w[kk * DD + col]);
}

// ---------------- subgraph branch: segment-sorted, in-place LDS, run-length reduced atomics ----------------
__global__ __launch_bounds__(256, 8) void submlp_mfma_kernel(
    const float* __restrict__ x, const int* __restrict__ snode, const int* __restrict__ sseg,
    const float* __restrict__ sn_g, const float* __restrict__ sn_b,
    const unsigned short* __restrict__ packB1, const float* __restrict__ p1b,
    const unsigned short* __restrict__ packB2, const float* __restrict__ p2b,
    float* __restrict__ accum, int M)
{
    __shared__ unsigned short sxs[64 * DD];   // 16 KB; reused in-place for hs, then fp32 out half-tile
    __shared__ int segS[64];
    float* outS = (float*)sxs;

    int tid = threadIdx.x;
    int lane = tid & 63, wid = tid >> 6;
    size_t m0 = (size_t)blockIdx.x * 64;

    if (tid < 64) {
        size_t row = m0 + tid;
        segS[tid] = (row < (size_t)M) ? sseg[row] : -1;
    }

    {
        int nid = 0;
        {
            size_t row = m0 + wid * 16 + (lane & 15);
            if (lane < 16 && row < (size_t)M) nid = snode[row];
        }
        float g0 = sn_g[2 * lane], g1 = sn_g[2 * lane + 1];
        float b0 = sn_b[2 * lane], b1 = sn_b[2 * lane + 1];
        #pragma unroll
        for (int r = 0; r < 16; r++) {
            int tr = wid * 16 + r;
            size_t row = m0 + tr;
            int node = __shfl(nid, r);
            float v0 = 0.f, v1 = 0.f;
            if (row < (size_t)M) {
                float2 xv = *(const float2*)&x[(size_t)node * DD + 2 * lane];
                v0 = xv.x; v1 = xv.y;
            }
            float s1 = v0 + v1, s2 = v0 * v0 + v1 * v1;
            #pragma unroll
            for (int o = 32; o >= 1; o >>= 1) { s1 += __shfl_xor(s1, o); s2 += __shfl_xor(s2, o); }
            float mean = s1 * (1.f / DD);
            float var  = s2 * (1.f / DD) - mean * mean;
            float rs = rsqrtf(var + 1e-5f);
            float n0 = (v0 - mean) * rs * g0 + b0;
            float n1 = (v1 - mean) * rs * g1 + b1;
            unsigned int uidx = ((unsigned)(tr * 64 + lane)) ^ (((unsigned)tr & 7u) << 2);
            ((unsigned int*)sxs)[uidx] = pack2bf16(n0, n1);
        }
    }
    __syncthreads();

    int wr = wid >> 1, wc = wid & 1;
    int rA = wr * 32 + (lane & 15);
    int kb = (lane >> 4) * 8;

    f32x4 acc[2][4];
    #pragma unroll
    for (int i = 0; i < 2; i++)
        #pragma unroll
        for (int j = 0; j < 4; j++) acc[i][j] = (f32x4){0.f, 0.f, 0.f, 0.f};

    #pragma unroll
    for (int kt = 0; kt < 4; kt++) {
        int k0 = kt * 32 + kb;
        bf16x8 a0 = *(const bf16x8*)&sxs[((rA)      * DD + k0) ^ ((rA & 7) << 3)];
        int rA1 = rA + 16;
        bf16x8 a1 = *(const bf16x8*)&sxs[((rA1)     * DD + k0) ^ ((rA1 & 7) << 3)];
        #pragma unroll
        for (int nc = 0; nc < 4; nc++) {
            bf16x8 b = *(const bf16x8*)&packB1[(((wc * 4 + nc) * 4 + kt) * 64 + lane) * 8];
            acc[0][nc] = __builtin_amdgcn_mfma_f32_16x16x32_bf16(a0, b, acc[0][nc], 0, 0, 0);
            acc[1][nc] = __builtin_amdgcn_mfma_f32_16x16x32_bf16(a1, b, acc[1][nc], 0, 0, 0);
        }
    }
    __syncthreads();

    {
        float bias1[4];
        #pragma unroll
        for (int nc = 0; nc < 4; nc++) bias1[nc] = p1b[wc * 64 + nc * 16 + (lane & 15)];
        #pragma unroll
        for (int mrf = 0; mrf < 2; mrf++) {
            int rbase = wr * 32 + mrf * 16 + (lane >> 4) * 4;
            #pragma unroll
            for (int nc = 0; nc < 4; nc++) {
                int col = wc * 64 + nc * 16 + (lane & 15);
                #pragma unroll
                for (int j = 0; j < 4; j++) {
                    float h = acc[mrf][nc][j] + bias1[nc];
                    h = h / (1.f + __expf(-h));
                    int rr = rbase + j;
                    sxs[(rr * DD + col) ^ ((rr & 7) << 3)] = f2bf(h);
                }
            }
        }
    }
    __syncthreads();

    f32x4 acc2[2][4];
    #pragma unroll
    for (int i = 0; i < 2; i++)
        #pragma unroll
        for (int j = 0; j < 4; j++) acc2[i][j] = (f32x4){0.f, 0.f, 0.f, 0.f};

    #pragma unroll
    for (int kt = 0; kt < 4; kt++) {
        int k0 = kt * 32 + kb;
        bf16x8 a0 = *(const bf16x8*)&sxs[((rA)      * DD + k0) ^ ((rA & 7) << 3)];
        int rA1 = rA + 16;
        bf16x8 a1 = *(const bf16x8*)&sxs[((rA1)     * DD + k0) ^ ((rA1 & 7) << 3)];
        #pragma unroll
        for (int nc = 0; nc < 4; nc++) {
            bf16x8 b = *(const bf16x8*)&packB2[(((wc * 4 + nc) * 4 + kt) * 64 + lane) * 8];
            acc2[0][nc] = __builtin_amdgcn_mfma_f32_16x16x32_bf16(a0, b, acc2[0][nc], 0, 0, 0);
            acc2[1][nc] = __builtin_amdgcn_mfma_f32_16x16x32_bf16(a1, b, acc2[1][nc], 0, 0, 0);
        }
    }
    __syncthreads();

    float bias2[4];
    #pragma unroll
    for (int nc = 0; nc < 4; nc++) bias2[nc] = p2b[wc * 64 + nc * 16 + (lane & 15)];

    #pragma unroll
    for (int half = 0; half < 2; half++) {
        if (wr == half) {
            #pragma unroll
            for (int mrf = 0; mrf < 2; mrf++) {
                int rloc = mrf * 16 + (lane >> 4) * 4;
                #pragma unroll
                for (int nc = 0; nc < 4; nc++) {
                    int col = wc * 64 + nc * 16 + (lane & 15);
                    #pragma unroll
                    for (int j = 0; j < 4; j++)
                        outS[(rloc + j) * DD + col] = acc2[mrf][nc][j] + bias2[nc];
                }
            }
        }
        __syncthreads();
        {
            int col = tid & 127;
            int r0 = (tid >> 7) * 16;
            float racc = 0.f;
            int cseg = -1;
            for (int r = r0; r < r0 + 16; r++) {
                int seg = segS[half * 32 + r];
                if (seg != cseg) {
                    if (cseg >= 0) atomicAdd(&accum[(size_t)cseg * DD + col], racc);
                    racc = 0.f; cseg = seg;
                }
                if (seg >= 0) racc += outS[r * DD + col];
            }
            if (cseg >= 0) atomicAdd(&accum[(size_t)cseg * DD + col], racc);
        }
        __syncthreads();
    }
}

// ---------------- final combine: LN + SiLU ----------------
__global__ __launch_bounds__(128) void final_kernel(
    const float* __restrict__ pre, const float* __restrict__ accum, const int* __restrict__ cnt,
    const float* __restrict__ on_g, const float* __restrict__ on_b,
    float* __restrict__ out, int N)
{
    __shared__ float red[4];
    int tid = threadIdx.x;
    int n = blockIdx.x;
    float inv = 1.f / fmaxf((float)cnt[n], 1.f);
    size_t o = (size_t)n * DD + tid;
    float val = pre[o] + accum[o] * inv;
    float s1 = val, s2 = val * val;
    for (int off = 32; off >= 1; off >>= 1) { s1 += __shfl_xor(s1, off); s2 += __shfl_xor(s2, off); }
    int w = tid >> 6;
    if ((tid & 63) == 0) { red[2 * w] = s1; red[2 * w + 1] = s2; }
    __syncthreads();
    float mean = (red[0] + red[2]) * (1.f / DD);
    float var  = (red[1] + red[3]) * (1.f / DD) - mean * mean;
    float ov = (val - mean) * rsqrtf(var + 1e-5f) * on_g[tid] + on_b[tid];
    out[o] = ov / (1.f + __expf(-ov));
}

extern "C" void kernel_launch(void* const* d_in, const int* in_sizes, int n_in,
                              void* d_out, int out_size, void* d_ws, size_t ws_size,
                              hipStream_t stream)
{
    const float* x         = (const float*)d_in[0];
    const int*   edge_index= (const int*)  d_in[1];
    const float* edge_attr = (const float*)d_in[2];
    const int*   sub_nodes = (const int*)  d_in[3];
    const int*   sub_ind   = (const int*)  d_in[4];
    const float* Wq = (const float*)d_in[5];  const float* bq = (const float*)d_in[6];
    const float* Wk = (const float*)d_in[7];  const float* bk = (const float*)d_in[8];
    const float* Wv = (const float*)d_in[9];  const float* bv = (const float*)d_in[10];
    const float* We = (const float*)d_in[11]; const float* be = (const float*)d_in[12];
    const float* Ws = (const float*)d_in[13]; const float* bs = (const float*)d_in[14];
    const float* sn_g = (const float*)d_in[15]; const float* sn_b = (const float*)d_in[16];
    const float* p1w = (const float*)d_in[17]; const float* p1b = (const float*)d_in[18];
    const float* p2w = (const float*)d_in[19]; const float* p2b = (const float*)d_in[20];
    const float* on_g = (const float*)d_in[21]; const float* on_b = (const float*)d_in[22];

    int N = in_sizes[0] / DD;
    int E = in_sizes[1] / 2;
    int M = in_sizes[3];
    float* out = (float*)d_out;

    unsigned short* packB1 = (unsigned short*)d_ws;
    unsigned short* packB2 = packB1 + DD * DD;
    size_t ND = (size_t)N * DD;
    float* q     = (float*)(packB2 + DD * DD);
    float* kvbuf = q + ND;            // 2*ND floats (interleaved k/v)
    float* pre   = kvbuf + 2 * ND;
    float* accum = pre + ND;
    int2* spair  = (int2*)(accum + ND);      // E pairs (8B-aligned: ND even)
    int* indptr  = (int*)(spair + E);        // N+1
    int* fill    = indptr + (N + 1);         // N
    int* deg     = fill + N;                 // N
    int* cnt     = deg + N;                  // N
    int* sindptr = cnt + N;                  // N+1
    int* sfill   = sindptr + (N + 1);        // N
    int* snode   = sfill + N;                // M
    int* sseg    = snode + M;                // M

    const int* srcA = edge_index;
    const int* dstA = edge_index + E;

    hipMemsetAsync(deg, 0, (size_t)N * sizeof(int), stream);
    hipMemsetAsync(cnt, 0, (size_t)N * sizeof(int), stream);
    hipMemsetAsync(accum, 0, ND * sizeof(float), stream);

    packw_kernel<<<(DD * DD + 255) / 256, 256, 0, stream>>>(p1w, packB1);
    packw_kernel<<<(DD * DD + 255) / 256, 256, 0, stream>>>(p2w, packB2);

    lin4_kernel<<<(N + 3) / 4, 128, 0, stream>>>(x, Wq, bq, Wk, bk, Wv, bv, Ws, bs, q, kvbuf, pre, N);
    count_kernel<<<2048, 256, 0, stream>>>(dstA, E, deg);
    count_kernel<<<2048, 256, 0, stream>>>(sub_ind, M, cnt);
    scan_kernel<<<1, 1024, 0, stream>>>(deg, N, indptr, fill);
    escatter_kernel<<<2048, 256, 0, stream>>>(srcA, dstA, E, fill, spair);
    scan_kernel<<<1, 1024, 0, stream>>>(cnt, N, sindptr, sfill);
    sscatter_kernel<<<2048, 256, 0, stream>>>(sub_nodes, sub_ind, M, sfill, snode, sseg);
    attn_kernel<<<(N + 7) / 8, 512, 0, stream>>>(q, kvbuf, edge_attr, We, be, indptr, spair, pre, N);
    submlp_mfma_kernel<<<(M + 63) / 64, 256, 0, stream>>>(x, snode, sseg, sn_g, sn_b,
                                                          packB1, p1b, packB2, p2b, accum, M);
    final_kernel<<<N, 128, 0, stream>>>(pre, accum, cnt, on_g, on_b, out, N);
}